// Round 5
// baseline (998.922 us; speedup 1.0000x reference)
//
#include <hip/hip_runtime.h>
#include <math.h>

#define BB 64
#define CC 2048
#define MM 196
#define DD 256
#define NTOT (BB * MM)  // 12544

typedef __attribute__((ext_vector_type(8))) short short8;
typedef __attribute__((ext_vector_type(4))) short short4v;
typedef __attribute__((ext_vector_type(4))) unsigned short ushort4v;
typedef __attribute__((ext_vector_type(4))) float f32x4;

__device__ __forceinline__ unsigned short bf16_rne(float f) {
  unsigned int u = __float_as_uint(f);
  unsigned int r = u + 0x7FFFu + ((u >> 16) & 1u);
  return (unsigned short)(r >> 16);
}

// ---------------------------------------------------------------------------
// K0: prep — split W into bf16 hi/lo (wh+wl), precompute BN scale/shift.
// (R0-proven verbatim)
// ---------------------------------------------------------------------------
__global__ __launch_bounds__(256) void k_prep(
    const float* __restrict__ w, const float* __restrict__ gamma,
    const float* __restrict__ beta, const float* __restrict__ rmean,
    const float* __restrict__ rvar, unsigned short* __restrict__ wh,
    unsigned short* __restrict__ wl, float* __restrict__ sclv,
    float* __restrict__ sftv) {
  const int e0 = (blockIdx.x * 256 + threadIdx.x) * 4;
  f32x4 v = *(const f32x4*)(w + e0);
  ushort4v h, l;
#pragma unroll
  for (int i = 0; i < 4; ++i) {
    unsigned short hb = bf16_rne(v[i]);
    float hf = __uint_as_float((unsigned int)hb << 16);
    h[i] = hb;
    l[i] = bf16_rne(v[i] - hf);
  }
  *(ushort4v*)(wh + e0) = h;
  *(ushort4v*)(wl + e0) = l;
  if (blockIdx.x == 0 && threadIdx.x < DD) {
    int d = threadIdx.x;
    float s = gamma[d] / sqrtf(rvar[d] + 1e-5f);
    sclv[d] = s;
    sftv[d] = beta[d] - rmean[d] * s;
  }
}

// ---------------------------------------------------------------------------
// K1: conv+BN+ReLU via bf16 split-3 MFMA (R0-proven verbatim, 142 us).
// ---------------------------------------------------------------------------
__global__ __launch_bounds__(256, 2) void k_conv(
    const float* __restrict__ x, const unsigned short* __restrict__ wh,
    const unsigned short* __restrict__ wl, const float* __restrict__ sclv,
    const float* __restrict__ sftv, float* __restrict__ yt) {
  const int tid = threadIdx.x;
  const int wid = tid >> 6, lane = tid & 63;
  const int quad = lane >> 4, l16 = lane & 15;
  const int n0 = blockIdx.x * 64;

  __shared__ unsigned short Xh[64][36];
  __shared__ unsigned short Xl[64][36];

  f32x4 acc[4][4];
#pragma unroll
  for (int i = 0; i < 4; ++i)
#pragma unroll
    for (int j = 0; j < 4; ++j) acc[i][j] = (f32x4)0.f;

  const int nX = tid & 63, kq = tid >> 6;
  const int gn = n0 + nX;
  const int bX = gn / MM, mX = gn - bX * MM;
  const float* xp = x + (size_t)bX * CC * MM + mX;

  float xr[8];
#pragma unroll
  for (int p = 0; p < 8; ++p) xr[p] = xp[(size_t)(kq * 8 + p) * MM];

  size_t aoff[4];
#pragma unroll
  for (int ds = 0; ds < 4; ++ds)
    aoff[ds] = (size_t)(wid * 64 + ds * 16 + l16) * CC + quad * 8;

  short8 Ah[4], Al[4], Ah2[4], Al2[4];
#pragma unroll
  for (int ds = 0; ds < 4; ++ds) {
    Ah[ds] = *(const short8*)(wh + aoff[ds]);
    Al[ds] = *(const short8*)(wl + aoff[ds]);
  }

  for (int c = 0; c < 64; ++c) {
    const int k0 = c * 32;
    __syncthreads();
    {
      ushort4v h0, h1, l0, l1;
#pragma unroll
      for (int p = 0; p < 4; ++p) {
        unsigned short hb = bf16_rne(xr[p]);
        float hf = __uint_as_float((unsigned int)hb << 16);
        h0[p] = hb;
        l0[p] = bf16_rne(xr[p] - hf);
      }
#pragma unroll
      for (int p = 0; p < 4; ++p) {
        unsigned short hb = bf16_rne(xr[4 + p]);
        float hf = __uint_as_float((unsigned int)hb << 16);
        h1[p] = hb;
        l1[p] = bf16_rne(xr[4 + p] - hf);
      }
      *(ushort4v*)&Xh[nX][kq * 8] = h0;
      *(ushort4v*)&Xh[nX][kq * 8 + 4] = h1;
      *(ushort4v*)&Xl[nX][kq * 8] = l0;
      *(ushort4v*)&Xl[nX][kq * 8 + 4] = l1;
    }
    __syncthreads();
    if (c < 63) {
#pragma unroll
      for (int p = 0; p < 8; ++p)
        xr[p] = xp[(size_t)(k0 + 32 + kq * 8 + p) * MM];
#pragma unroll
      for (int ds = 0; ds < 4; ++ds) {
        Ah2[ds] = *(const short8*)(wh + aoff[ds] + k0 + 32);
        Al2[ds] = *(const short8*)(wl + aoff[ds] + k0 + 32);
      }
    }
#pragma unroll
    for (int ns = 0; ns < 4; ++ns) {
      const unsigned short* bp = &Xh[ns * 16 + l16][quad * 8];
      short4v b0 = *(const short4v*)bp;
      short4v b1 = *(const short4v*)(bp + 4);
      short8 Bh = __builtin_shufflevector(b0, b1, 0, 1, 2, 3, 4, 5, 6, 7);
      const unsigned short* bq = &Xl[ns * 16 + l16][quad * 8];
      short4v c0 = *(const short4v*)bq;
      short4v c1 = *(const short4v*)(bq + 4);
      short8 Bl = __builtin_shufflevector(c0, c1, 0, 1, 2, 3, 4, 5, 6, 7);
#pragma unroll
      for (int ds = 0; ds < 4; ++ds) {
        acc[ds][ns] = __builtin_amdgcn_mfma_f32_16x16x32_bf16(
            Ah[ds], Bh, acc[ds][ns], 0, 0, 0);
        acc[ds][ns] = __builtin_amdgcn_mfma_f32_16x16x32_bf16(
            Ah[ds], Bl, acc[ds][ns], 0, 0, 0);
        acc[ds][ns] = __builtin_amdgcn_mfma_f32_16x16x32_bf16(
            Al[ds], Bh, acc[ds][ns], 0, 0, 0);
      }
    }
#pragma unroll
    for (int ds = 0; ds < 4; ++ds) {
      Ah[ds] = Ah2[ds];
      Al[ds] = Al2[ds];
    }
  }

#pragma unroll
  for (int ds = 0; ds < 4; ++ds) {
    const int dbase = wid * 64 + ds * 16 + quad * 4;
    f32x4 s4 = *(const f32x4*)(sclv + dbase);
    f32x4 f4 = *(const f32x4*)(sftv + dbase);
#pragma unroll
    for (int ns = 0; ns < 4; ++ns) {
      const int n = n0 + ns * 16 + l16;
      const int b = n / MM, m = n - b * MM;
      f32x4 o;
#pragma unroll
      for (int r = 0; r < 4; ++r) {
        float v = fmaf(acc[ds][ns][r], s4[r], f4[r]);
        o[r] = v > 0.f ? v : 0.f;
      }
      *(f32x4*)(yt + ((size_t)b * MM + m) * DD + dbase) = o;
    }
  }
}

// ---------------------------------------------------------------------------
// K2: per-(b,d) mean over m in fp64 (R0-proven) + zero the 16 per-batch sync
// flags that k_persist uses (they live in out[b*32896 + 0..15], overwritten
// by real output at the very end of k_persist).
// ---------------------------------------------------------------------------
__global__ __launch_bounds__(256) void k_means(const float* __restrict__ yt,
                                               double* __restrict__ mean,
                                               float* __restrict__ out) {
  const int b = blockIdx.x;
  const int d = threadIdx.x;
  if (d < 16) ((int*)(out + (size_t)b * 32896))[d] = 0;
  const float* p = yt + (size_t)b * MM * DD + d;
  double s0 = 0, s1 = 0, s2 = 0, s3 = 0;
  for (int m = 0; m < MM; m += 4) {
    s0 += (double)p[(size_t)(m + 0) * DD];
    s1 += (double)p[(size_t)(m + 1) * DD];
    s2 += (double)p[(size_t)(m + 2) * DD];
    s3 += (double)p[(size_t)(m + 3) * DD];
  }
  mean[b * DD + d] = (s0 + s1 + s2 + s3) * (1.0 / MM);
}

// ---------------------------------------------------------------------------
// K3: cov[b] = (Y-mu)(Y-mu)^T / M + eps*I  in fp64 (R0-proven verbatim).
// ---------------------------------------------------------------------------
__global__ __launch_bounds__(256) void k_cov(const float* __restrict__ yt,
                                             const double* __restrict__ mean,
                                             double* __restrict__ cov) {
  const int b = blockIdx.x;
  const int t = blockIdx.y;
  const int ti = (t < 1) ? 0 : (t < 3) ? 1 : (t < 6) ? 2 : 3;
  const int tj = t - (ti * (ti + 1)) / 2;
  const int i0 = ti * 64, j0 = tj * 64;
  const int tid = threadIdx.x;
  const int tx = tid & 15, ty = tid >> 4;

  __shared__ double As[32][66];
  __shared__ double Bs[32][66];

  double acc[4][4];
#pragma unroll
  for (int i = 0; i < 4; ++i)
#pragma unroll
    for (int j = 0; j < 4; ++j) acc[i][j] = 0.0;

  const int dl = tid & 63, kl = tid >> 6;
  const double mA = mean[b * DD + i0 + dl];
  const double mB = mean[b * DD + j0 + dl];
  const float* ybase = yt + (size_t)b * MM * DD;

  for (int k0 = 0; k0 < MM; k0 += 32) {
    __syncthreads();
#pragma unroll
    for (int p = 0; p < 8; ++p) {
      int k = kl + p * 4;
      int m = k0 + k;
      double av = 0.0, bv = 0.0;
      if (m < MM) {
        av = (double)ybase[(size_t)m * DD + i0 + dl] - mA;
        bv = (double)ybase[(size_t)m * DD + j0 + dl] - mB;
      }
      As[k][dl] = av;
      Bs[k][dl] = bv;
    }
    __syncthreads();
#pragma unroll
    for (int k = 0; k < 32; ++k) {
      double a[4], bv[4];
#pragma unroll
      for (int i = 0; i < 4; ++i) a[i] = As[k][ty * 4 + i];
#pragma unroll
      for (int j = 0; j < 4; ++j) bv[j] = Bs[k][tx * 4 + j];
#pragma unroll
      for (int i = 0; i < 4; ++i)
#pragma unroll
        for (int j = 0; j < 4; ++j) acc[i][j] = fma(a[i], bv[j], acc[i][j]);
    }
  }

  double* cb = cov + (size_t)b * DD * DD;
#pragma unroll
  for (int i = 0; i < 4; ++i) {
#pragma unroll
    for (int j = 0; j < 4; ++j) {
      int gi = i0 + ty * 4 + i, gj = j0 + tx * 4 + j;
      double v = acc[i][j] * (1.0 / MM);
      if (gi == gj) v += 1e-6;
      cb[(size_t)gi * DD + gj] = v;
      if (ti != tj) cb[(size_t)gj * DD + gi] = v;
    }
  }
}

// ---------------------------------------------------------------------------
// Persistent-DAG sync helpers (device-scope acquire/release).
// ---------------------------------------------------------------------------
__device__ __forceinline__ void block_wait(int* p, int target) {
  if (threadIdx.x == 0) {
    while (__hip_atomic_load(p, __ATOMIC_RELAXED, __HIP_MEMORY_SCOPE_AGENT) <
           target)
      __builtin_amdgcn_s_sleep(1);
  }
  __syncthreads();
  __builtin_amdgcn_fence(__ATOMIC_ACQUIRE, "agent");
}

__device__ __forceinline__ void block_signal(int* p) {
  __syncthreads();  // all block stores drained (vmcnt(0) at barrier)
  if (threadIdx.x == 0)
    __hip_atomic_fetch_add(p, 1, __ATOMIC_RELEASE, __HIP_MEMORY_SCOPE_AGENT);
}

__device__ __forceinline__ int ntiles_of(int s) {
  int S = 224 - 32 * s;
  if (S <= 0) return 0;
  int nt = (S + 63) >> 6;
  return nt * (nt + 1) / 2;
}

// ---------------------------------------------------------------------------
// K4: persistent Cholesky DAG.  Grid (BB, 7).  Per batch: block y=0 runs all
// 8 lookahead panel steps (R4-proven register-panel code) then the triuvec
// out-phase; blocks y=1..6 run the proven trailing-tile microkernel per step.
// Ordering via per-batch flags in out[b*32896+0..15]: P[kb]=panel done,
// T[s]=trailing tiles done.  Same dep structure the 8 launches enforced:
//   trailing s:  needs P[s-1] (panel data) and T[s-1] (RMW order);
//   panel kb:    needs T[kb-1] (kb>=2); syrk self-corrects for panel kb-1.
// Panel kb's cols [j0,j0+32) are disjoint from trailing kb's write region
// [j0+32,256)^2, so panel kb || trailing kb is safe (the proven lookahead).
// All 448 blocks co-resident (launch_bounds (256,2) + 34KB LDS => 2/CU).
// ---------------------------------------------------------------------------
__global__ __launch_bounds__(256, 2) void k_persist(double* __restrict__ cov,
                                                    float* out) {
  const int b = blockIdx.x;
  const int tid = threadIdx.x;
  double* A = cov + (size_t)b * DD * DD;
  int* flg = (int*)(out + (size_t)b * 32896);
  int* P = flg;      // [0..7]
  int* T = flg + 8;  // [0..7]

  __shared__ double sh[4224];  // 33,792 B union

  if (blockIdx.y == 0) {
    // ------------------------- panel runner --------------------------------
    double(*LpTop)[33] = (double(*)[33])sh;          // 32x33
    double(*L11s)[33] = (double(*)[33])(sh + 1056);  // 32x33
    double* rpivs = sh + 2112;

    for (int kb = 0; kb < 8; ++kb) {
      const int j0 = kb * 32;
      const int R = DD - j0;
      const int pj = j0 - 32;
      if (kb >= 2) block_wait(&T[kb - 1], ntiles_of(kb - 1));

      // stage this thread's panel row in registers
      double sp[32];
      const double* rowp = A + (size_t)(j0 + tid) * DD;
      if (tid < R) {
#pragma unroll
        for (int c = 0; c < 32; ++c) sp[c] = rowp[j0 + c];
      }

      if (kb > 0) {
        double lp[32];
        if (tid < R) {
#pragma unroll
          for (int c = 0; c < 32; ++c) lp[c] = rowp[pj + c];
        }
        __syncthreads();  // LDS WAR vs previous iteration
        if (tid < 32) {
#pragma unroll
          for (int c = 0; c < 32; ++c) LpTop[tid][c] = lp[c];
        }
        __syncthreads();
        // syrk correction: sp[c] -= <lp, Lp(row j0+c)>
        if (tid < R) {
#pragma unroll
          for (int c = 0; c < 32; ++c) {
            double a = 0.0;
#pragma unroll
            for (int p = 0; p < 32; ++p) a = fma(lp[p], LpTop[c][p], a);
            sp[c] -= a;
          }
        }
      }

      // 32x32 factor on wave-0 lanes (proven shuffle chain)
      if (tid < 32) {
        double rpkeep = 0.0;
#pragma unroll
        for (int j = 0; j < 32; ++j) {
          double dj = __shfl(sp[j], j);
          double piv = sqrt(dj);
          double rp = 1.0 / piv;
          if (tid == j) {
            sp[j] = piv;
            rpkeep = rp;
          } else {
            sp[j] = sp[j] * rp;
          }
          double lij = sp[j];
#pragma unroll
          for (int k = j + 1; k < 32; ++k) {
            double ck = __shfl(lij, k);
            sp[k] -= lij * ck;
          }
        }
#pragma unroll
        for (int k = 0; k < 32; ++k) L11s[tid][k] = (k <= tid) ? sp[k] : 0.0;
        rpivs[tid] = rpkeep;
        for (int k = 0; k <= tid; ++k)
          A[(size_t)(j0 + tid) * DD + j0 + k] = sp[k];
      }
      __syncthreads();

      // trsm rows j0+32..255 (proven, row-per-thread)
      if (tid >= 32 && tid < R) {
#pragma unroll
        for (int j = 0; j < 32; ++j) {
          double s = sp[j];
#pragma unroll
          for (int k = 0; k < 32; ++k)
            if (k < j) s -= sp[k] * L11s[j][k];
          sp[j] = s * rpivs[j];
        }
        double* dst = A + (size_t)(j0 + tid) * DD + j0;
#pragma unroll
        for (int k = 0; k < 32; ++k) dst[k] = sp[k];
      }
      block_signal(&P[kb]);
    }

    // --------------- triuvec out-phase (proven, per-batch) -----------------
    float* Sf = (float*)sh;  // 64x65 floats
    for (int t = 0; t < 10; ++t) {
      int ti = 0, tj = t;
      while (tj >= 4 - ti) {
        tj -= (4 - ti);
        ti++;
      }
      tj += ti;
      __syncthreads();
      for (int e = tid; e < 4096; e += 256) {
        int jj = e >> 6, ii = e & 63;
        Sf[jj * 65 + ii] =
            (float)A[(size_t)(tj * 64 + jj) * DD + ti * 64 + ii];
      }
      __syncthreads();
      for (int e = tid; e < 4096; e += 256) {
        int ii = e >> 6, jj = e & 63;
        int i = ti * 64 + ii, j = tj * 64 + jj;
        if (j < i) continue;
        float v = Sf[jj * 65 + ii];
        if (i == j) v = 2.0f * logf(v);
        int off = i * DD - (i * (i - 1)) / 2 + (j - i);
        out[(size_t)b * 32896 + off] = v;
      }
    }
  } else {
    // ------------------------ trailing worker ------------------------------
    const int w = (int)blockIdx.y - 1;  // 0..5
    double(*Ea)[33] = (double(*)[33])sh;           // 64x33
    double(*Eb)[33] = (double(*)[33])(sh + 2112);  // 64x33
    const int txl = tid & 15, tyl = tid >> 4;
    const int bi = tyl * 4, bj = txl * 4;

    for (int s = 1; s <= 6; ++s) {
      if (w >= ntiles_of(s)) continue;
      block_wait(&P[s - 1], 1);
      if (s >= 2) block_wait(&T[s - 1], ntiles_of(s - 1));

      const int j0 = s * 32;
      const int o = j0 + 32;
      const int S = DD - o;
      const int pj = j0 - 32;
      int tI = 0, tJ = w;
      while (tJ > tI) {
        tJ -= (tI + 1);
        tI++;
      }
      const int i0 = tI * 64, jj0 = tJ * 64;

      for (int e = tid; e < 64 * 32; e += 256) {
        int r = e >> 5, c = e & 31;
        Ea[r][c] = (i0 + r < S) ? A[(size_t)(o + i0 + r) * DD + pj + c] : 0.0;
        Eb[r][c] =
            (jj0 + r < S) ? A[(size_t)(o + jj0 + r) * DD + pj + c] : 0.0;
      }
      __syncthreads();

      double sacc[4][4];
#pragma unroll
      for (int i = 0; i < 4; ++i)
#pragma unroll
        for (int j = 0; j < 4; ++j) sacc[i][j] = 0.0;

#pragma unroll
      for (int k = 0; k < 32; ++k) {
        double a[4], bv[4];
#pragma unroll
        for (int i = 0; i < 4; ++i) a[i] = Ea[bi + i][k];
#pragma unroll
        for (int j = 0; j < 4; ++j) bv[j] = Eb[bj + j][k];
#pragma unroll
        for (int i = 0; i < 4; ++i)
#pragma unroll
          for (int j = 0; j < 4; ++j)
            sacc[i][j] = fma(a[i], bv[j], sacc[i][j]);
      }

#pragma unroll
      for (int i = 0; i < 4; ++i)
#pragma unroll
        for (int j = 0; j < 4; ++j) {
          int gi = i0 + bi + i, gj = jj0 + bj + j;
          if (gi < S && gj < S && gi >= gj)
            A[(size_t)(o + gi) * DD + (o + gj)] -= sacc[i][j];
        }
      block_signal(&T[s]);
    }
  }
}

extern "C" void kernel_launch(void* const* d_in, const int* in_sizes, int n_in,
                              void* d_out, int out_size, void* d_ws,
                              size_t ws_size, hipStream_t stream) {
  const float* x = (const float*)d_in[0];
  const float* w = (const float*)d_in[1];
  const float* gamma = (const float*)d_in[2];
  const float* beta = (const float*)d_in[3];
  const float* rmean = (const float*)d_in[4];
  const float* rvar = (const float*)d_in[5];
  float* out = (float*)d_out;

  char* ws = (char*)d_ws;
  float* yt = (float*)ws;                           // 12,845,056 B
  double* mean = (double*)(ws + 12845056);          //    131,072 B
  double* cov = (double*)(ws + 12845056 + 131072);  // 33,554,432 B
  // alias W-prep buffers into cov (consumed by k_conv before cov is written)
  unsigned short* wh = (unsigned short*)cov;  // 1,048,576 B
  unsigned short* wl = wh + (DD * CC);        // 1,048,576 B
  float* sclv = (float*)(wl + (DD * CC));     //     1,024 B
  float* sftv = sclv + DD;                    //     1,024 B

  k_prep<<<512, 256, 0, stream>>>(w, gamma, beta, rmean, rvar, wh, wl, sclv,
                                  sftv);
  k_conv<<<NTOT / 64, 256, 0, stream>>>(x, wh, wl, sclv, sftv, yt);
  k_means<<<BB, 256, 0, stream>>>(yt, mean, out);
  k_cov<<<dim3(BB, 10), 256, 0, stream>>>(yt, mean, cov);
  k_persist<<<dim3(BB, 7), 256, 0, stream>>>(cov, out);
}

// Round 6
// 652.481 us; speedup vs baseline: 1.5310x; 1.5310x over previous
//
#include <hip/hip_runtime.h>
#include <math.h>

#define BB 64
#define CC 2048
#define MM 196
#define DD 256
#define NTOT (BB * MM)  // 12544

typedef __attribute__((ext_vector_type(8))) short short8;
typedef __attribute__((ext_vector_type(4))) short short4v;
typedef __attribute__((ext_vector_type(4))) unsigned short ushort4v;
typedef __attribute__((ext_vector_type(4))) float f32x4;

__device__ __forceinline__ unsigned short bf16_rne(float f) {
  unsigned int u = __float_as_uint(f);
  unsigned int r = u + 0x7FFFu + ((u >> 16) & 1u);
  return (unsigned short)(r >> 16);
}

// ---------------------------------------------------------------------------
// K0: prep — split W into bf16 hi/lo (wh+wl), precompute BN scale/shift.
// (R0-proven verbatim)
// ---------------------------------------------------------------------------
__global__ __launch_bounds__(256) void k_prep(
    const float* __restrict__ w, const float* __restrict__ gamma,
    const float* __restrict__ beta, const float* __restrict__ rmean,
    const float* __restrict__ rvar, unsigned short* __restrict__ wh,
    unsigned short* __restrict__ wl, float* __restrict__ sclv,
    float* __restrict__ sftv) {
  const int e0 = (blockIdx.x * 256 + threadIdx.x) * 4;
  f32x4 v = *(const f32x4*)(w + e0);
  ushort4v h, l;
#pragma unroll
  for (int i = 0; i < 4; ++i) {
    unsigned short hb = bf16_rne(v[i]);
    float hf = __uint_as_float((unsigned int)hb << 16);
    h[i] = hb;
    l[i] = bf16_rne(v[i] - hf);
  }
  *(ushort4v*)(wh + e0) = h;
  *(ushort4v*)(wl + e0) = l;
  if (blockIdx.x == 0 && threadIdx.x < DD) {
    int d = threadIdx.x;
    float s = gamma[d] / sqrtf(rvar[d] + 1e-5f);
    sclv[d] = s;
    sftv[d] = beta[d] - rmean[d] * s;
  }
}

// ---------------------------------------------------------------------------
// K1: conv+BN+ReLU via bf16 split-3 MFMA.  R6 pipeline restructure:
// double-buffered LDS, ONE barrier per K-iteration, 2-deep x prefetch
// (x tile c+2 issued during iter c, consumed by the convert at iter c+1).
// Per-iteration region: {convert+write tile c+1 | MFMA tile c | issue x
// loads c+2 | W prefetch c+1} all barrier-free so global-load latency
// hides under MFMA.  Math (converts, MFMA order, epilogue) identical to
// the R0-proven version.
// ---------------------------------------------------------------------------
__global__ __launch_bounds__(256, 2) void k_conv(
    const float* __restrict__ x, const unsigned short* __restrict__ wh,
    const unsigned short* __restrict__ wl, const float* __restrict__ sclv,
    const float* __restrict__ sftv, float* __restrict__ yt) {
  const int tid = threadIdx.x;
  const int wid = tid >> 6, lane = tid & 63;
  const int quad = lane >> 4, l16 = lane & 15;
  const int n0 = blockIdx.x * 64;

  __shared__ unsigned short Xh[2][64][36];
  __shared__ unsigned short Xl[2][64][36];

  f32x4 acc[4][4];
#pragma unroll
  for (int i = 0; i < 4; ++i)
#pragma unroll
    for (int j = 0; j < 4; ++j) acc[i][j] = (f32x4)0.f;

  const int nX = tid & 63, kq = tid >> 6;
  const int gn = n0 + nX;
  const int bX = gn / MM, mX = gn - bX * MM;
  const float* xp = x + (size_t)bX * CC * MM + mX;

  size_t aoff[4];
#pragma unroll
  for (int ds = 0; ds < 4; ++ds)
    aoff[ds] = (size_t)(wid * 64 + ds * 16 + l16) * CC + quad * 8;

  short8 Ah[4], Al[4], Ah2[4], Al2[4];
#pragma unroll
  for (int ds = 0; ds < 4; ++ds) {
    Ah[ds] = *(const short8*)(wh + aoff[ds]);
    Al[ds] = *(const short8*)(wl + aoff[ds]);
  }

  float xr[8];
  // tile 0 loads
#pragma unroll
  for (int p = 0; p < 8; ++p) xr[p] = xp[(size_t)(kq * 8 + p) * MM];
  // convert + write tile 0 into buf 0
  {
    ushort4v h0, h1, l0, l1;
#pragma unroll
    for (int p = 0; p < 4; ++p) {
      unsigned short hb = bf16_rne(xr[p]);
      float hf = __uint_as_float((unsigned int)hb << 16);
      h0[p] = hb;
      l0[p] = bf16_rne(xr[p] - hf);
    }
#pragma unroll
    for (int p = 0; p < 4; ++p) {
      unsigned short hb = bf16_rne(xr[4 + p]);
      float hf = __uint_as_float((unsigned int)hb << 16);
      h1[p] = hb;
      l1[p] = bf16_rne(xr[4 + p] - hf);
    }
    *(ushort4v*)&Xh[0][nX][kq * 8] = h0;
    *(ushort4v*)&Xh[0][nX][kq * 8 + 4] = h1;
    *(ushort4v*)&Xl[0][nX][kq * 8] = l0;
    *(ushort4v*)&Xl[0][nX][kq * 8 + 4] = l1;
  }
  // tile 1 loads into xr
#pragma unroll
  for (int p = 0; p < 8; ++p) xr[p] = xp[(size_t)(32 + kq * 8 + p) * MM];
  __syncthreads();

  for (int c = 0; c < 64; ++c) {
    const int buf = c & 1;
    if (c < 63) {
      // stage tile c+1 (data in xr) into buf^1
      ushort4v h0, h1, l0, l1;
#pragma unroll
      for (int p = 0; p < 4; ++p) {
        unsigned short hb = bf16_rne(xr[p]);
        float hf = __uint_as_float((unsigned int)hb << 16);
        h0[p] = hb;
        l0[p] = bf16_rne(xr[p] - hf);
      }
#pragma unroll
      for (int p = 0; p < 4; ++p) {
        unsigned short hb = bf16_rne(xr[4 + p]);
        float hf = __uint_as_float((unsigned int)hb << 16);
        h1[p] = hb;
        l1[p] = bf16_rne(xr[4 + p] - hf);
      }
      *(ushort4v*)&Xh[buf ^ 1][nX][kq * 8] = h0;
      *(ushort4v*)&Xh[buf ^ 1][nX][kq * 8 + 4] = h1;
      *(ushort4v*)&Xl[buf ^ 1][nX][kq * 8] = l0;
      *(ushort4v*)&Xl[buf ^ 1][nX][kq * 8 + 4] = l1;
      // issue x loads for tile c+2 (2-iteration prefetch depth)
      if (c < 62) {
#pragma unroll
        for (int p = 0; p < 8; ++p)
          xr[p] = xp[(size_t)((c + 2) * 32 + kq * 8 + p) * MM];
      }
      // W prefetch tile c+1
#pragma unroll
      for (int ds = 0; ds < 4; ++ds) {
        Ah2[ds] = *(const short8*)(wh + aoff[ds] + (c + 1) * 32);
        Al2[ds] = *(const short8*)(wl + aoff[ds] + (c + 1) * 32);
      }
    }
    // MFMA tile c from buf
#pragma unroll
    for (int ns = 0; ns < 4; ++ns) {
      const unsigned short* bp = &Xh[buf][ns * 16 + l16][quad * 8];
      short4v b0 = *(const short4v*)bp;
      short4v b1 = *(const short4v*)(bp + 4);
      short8 Bh = __builtin_shufflevector(b0, b1, 0, 1, 2, 3, 4, 5, 6, 7);
      const unsigned short* bq = &Xl[buf][ns * 16 + l16][quad * 8];
      short4v c0 = *(const short4v*)bq;
      short4v c1 = *(const short4v*)(bq + 4);
      short8 Bl = __builtin_shufflevector(c0, c1, 0, 1, 2, 3, 4, 5, 6, 7);
#pragma unroll
      for (int ds = 0; ds < 4; ++ds) {
        acc[ds][ns] = __builtin_amdgcn_mfma_f32_16x16x32_bf16(
            Ah[ds], Bh, acc[ds][ns], 0, 0, 0);
        acc[ds][ns] = __builtin_amdgcn_mfma_f32_16x16x32_bf16(
            Ah[ds], Bl, acc[ds][ns], 0, 0, 0);
        acc[ds][ns] = __builtin_amdgcn_mfma_f32_16x16x32_bf16(
            Al[ds], Bh, acc[ds][ns], 0, 0, 0);
      }
    }
    __syncthreads();
    if (c < 63) {
#pragma unroll
      for (int ds = 0; ds < 4; ++ds) {
        Ah[ds] = Ah2[ds];
        Al[ds] = Al2[ds];
      }
    }
  }

  // epilogue: BN + ReLU, store yt[b][m][d] (R0-proven verbatim)
#pragma unroll
  for (int ds = 0; ds < 4; ++ds) {
    const int dbase = wid * 64 + ds * 16 + quad * 4;
    f32x4 s4 = *(const f32x4*)(sclv + dbase);
    f32x4 f4 = *(const f32x4*)(sftv + dbase);
#pragma unroll
    for (int ns = 0; ns < 4; ++ns) {
      const int n = n0 + ns * 16 + l16;
      const int b = n / MM, m = n - b * MM;
      f32x4 o;
#pragma unroll
      for (int r = 0; r < 4; ++r) {
        float v = fmaf(acc[ds][ns][r], s4[r], f4[r]);
        o[r] = v > 0.f ? v : 0.f;
      }
      *(f32x4*)(yt + ((size_t)b * MM + m) * DD + dbase) = o;
    }
  }
}

// ---------------------------------------------------------------------------
// K3: cov[b] = (Y-mu)(Y-mu)^T / M + eps*I in fp64.  R6: the per-block means
// (mA/mB) are computed in-kernel (fp64, 2-way m-split + LDS combine) —
// k_means dispatch deleted.  Staging/microkernel are R0-proven verbatim.
// ---------------------------------------------------------------------------
__global__ __launch_bounds__(256) void k_cov(const float* __restrict__ yt,
                                             double* __restrict__ cov) {
  const int b = blockIdx.x;
  const int t = blockIdx.y;
  const int ti = (t < 1) ? 0 : (t < 3) ? 1 : (t < 6) ? 2 : 3;
  const int tj = t - (ti * (ti + 1)) / 2;
  const int i0 = ti * 64, j0 = tj * 64;
  const int tid = threadIdx.x;
  const int tx = tid & 15, ty = tid >> 4;

  __shared__ double As[32][66];
  __shared__ double Bs[32][66];
  __shared__ double Ms[4][64];

  double acc[4][4];
#pragma unroll
  for (int i = 0; i < 4; ++i)
#pragma unroll
    for (int j = 0; j < 4; ++j) acc[i][j] = 0.0;

  const int dl = tid & 63, kl = tid >> 6;
  const float* ybase = yt + (size_t)b * MM * DD;

  // fused mean: groups 0,1 -> i-range (m halves); groups 2,3 -> j-range
  {
    const int base_d = ((kl < 2) ? i0 : j0) + dl;
    const int mlo = (kl & 1) ? 98 : 0;
    const int mhi = (kl & 1) ? 196 : 98;
    double s = 0.0;
    for (int m = mlo; m < mhi; ++m)
      s += (double)ybase[(size_t)m * DD + base_d];
    Ms[kl][dl] = s;
  }
  __syncthreads();
  const double mA = (Ms[0][dl] + Ms[1][dl]) * (1.0 / MM);
  const double mB = (Ms[2][dl] + Ms[3][dl]) * (1.0 / MM);

  for (int k0 = 0; k0 < MM; k0 += 32) {
    __syncthreads();
#pragma unroll
    for (int p = 0; p < 8; ++p) {
      int k = kl + p * 4;
      int m = k0 + k;
      double av = 0.0, bv = 0.0;
      if (m < MM) {
        av = (double)ybase[(size_t)m * DD + i0 + dl] - mA;
        bv = (double)ybase[(size_t)m * DD + j0 + dl] - mB;
      }
      As[k][dl] = av;
      Bs[k][dl] = bv;
    }
    __syncthreads();
#pragma unroll
    for (int k = 0; k < 32; ++k) {
      double a[4], bv[4];
#pragma unroll
      for (int i = 0; i < 4; ++i) a[i] = As[k][ty * 4 + i];
#pragma unroll
      for (int j = 0; j < 4; ++j) bv[j] = Bs[k][tx * 4 + j];
#pragma unroll
      for (int i = 0; i < 4; ++i)
#pragma unroll
        for (int j = 0; j < 4; ++j) acc[i][j] = fma(a[i], bv[j], acc[i][j]);
    }
  }

  double* cb = cov + (size_t)b * DD * DD;
#pragma unroll
  for (int i = 0; i < 4; ++i) {
#pragma unroll
    for (int j = 0; j < 4; ++j) {
      int gi = i0 + ty * 4 + i, gj = j0 + tx * 4 + j;
      double v = acc[i][j] * (1.0 / MM);
      if (gi == gj) v += 1e-6;
      cb[(size_t)gi * DD + gj] = v;
      if (ti != tj) cb[(size_t)gj * DD + gi] = v;
    }
  }
}

// ---------------------------------------------------------------------------
// K4: lookahead Cholesky step kb (R4-proven verbatim: register panel,
// 33.8KB LDS, kb==7 panel block emits triuvec output).
// ---------------------------------------------------------------------------
__global__ __launch_bounds__(256) void k_panel3(double* __restrict__ cov,
                                                float* __restrict__ out,
                                                int kb) {
  const int b = blockIdx.x;
  double* A = cov + (size_t)b * DD * DD;
  const int j0 = kb * 32;
  const int tid = threadIdx.x;

  __shared__ double sh[4224];  // 33,792 B union

  if (blockIdx.y == 0) {
    double(*LpTop)[33] = (double(*)[33])sh;          // 32x33
    double(*L11s)[33] = (double(*)[33])(sh + 1056);  // 32x33
    double* rpivs = sh + 2112;
    const int R = DD - j0;
    const int pj = j0 - 32;

    // stage this thread's panel row in registers
    double sp[32];
    const double* rowp = A + (size_t)(j0 + tid) * DD;
    if (tid < R) {
#pragma unroll
      for (int c = 0; c < 32; ++c) sp[c] = rowp[j0 + c];
    }

    if (kb > 0) {
      double lp[32];
      if (tid < R) {
#pragma unroll
        for (int c = 0; c < 32; ++c) lp[c] = rowp[pj + c];
      }
      if (tid < 32) {
#pragma unroll
        for (int c = 0; c < 32; ++c) LpTop[tid][c] = lp[c];
      }
      __syncthreads();
      // syrk correction: sp[c] -= <lp, Lp(row j0+c)>
      if (tid < R) {
#pragma unroll
        for (int c = 0; c < 32; ++c) {
          double a = 0.0;
#pragma unroll
          for (int p = 0; p < 32; ++p) a = fma(lp[p], LpTop[c][p], a);
          sp[c] -= a;
        }
      }
    }

    // 32x32 factor on wave-0 lanes (proven shuffle chain)
    if (tid < 32) {
      double rpkeep = 0.0;
#pragma unroll
      for (int j = 0; j < 32; ++j) {
        double dj = __shfl(sp[j], j);
        double piv = sqrt(dj);
        double rp = 1.0 / piv;
        if (tid == j) {
          sp[j] = piv;
          rpkeep = rp;
        } else {
          sp[j] = sp[j] * rp;
        }
        double lij = sp[j];
#pragma unroll
        for (int k = j + 1; k < 32; ++k) {
          double ck = __shfl(lij, k);
          sp[k] -= lij * ck;
        }
      }
#pragma unroll
      for (int k = 0; k < 32; ++k) L11s[tid][k] = (k <= tid) ? sp[k] : 0.0;
      rpivs[tid] = rpkeep;
      for (int k = 0; k <= tid; ++k)
        A[(size_t)(j0 + tid) * DD + j0 + k] = sp[k];
    }
    __syncthreads();

    // trsm rows j0+32..255 (proven, row-per-thread)
    if (tid >= 32 && tid < R) {
#pragma unroll
      for (int j = 0; j < 32; ++j) {
        double s = sp[j];
#pragma unroll
        for (int k = 0; k < 32; ++k)
          if (k < j) s -= sp[k] * L11s[j][k];
        sp[j] = s * rpivs[j];
      }
      double* dst = A + (size_t)(j0 + tid) * DD + j0;
#pragma unroll
      for (int k = 0; k < 32; ++k) dst[k] = sp[k];
    }

    // ---- kb==7: whole factorization done for this batch; emit triuvec ----
    if (kb == 7) {
      float* Sf = (float*)sh;  // 64x65 floats
      __syncthreads();
      for (int t = 0; t < 10; ++t) {
        int ti = 0, tj = t;
        while (tj >= 4 - ti) {
          tj -= (4 - ti);
          ti++;
        }
        tj += ti;
        __syncthreads();
        for (int e = tid; e < 4096; e += 256) {
          int jj = e >> 6, ii = e & 63;
          Sf[jj * 65 + ii] =
              (float)A[(size_t)(tj * 64 + jj) * DD + ti * 64 + ii];
        }
        __syncthreads();
        for (int e = tid; e < 4096; e += 256) {
          int ii = e >> 6, jj = e & 63;
          int i = ti * 64 + ii, j = tj * 64 + jj;
          if (j < i) continue;
          float v = Sf[jj * 65 + ii];
          if (i == j) v = 2.0f * logf(v);
          int off = i * DD - (i * (i - 1)) / 2 + (j - i);
          out[(size_t)b * 32896 + off] = v;
        }
      }
    }
  } else {
    // trailing: apply panel kb-1 to [o,256)^2 (R0-proven verbatim, Ea/Eb)
    const int o = j0 + 32;
    const int S = DD - o;
    const int pj = j0 - 32;
    int tI = 0, tJ = (int)blockIdx.y - 1;
    while (tJ > tI) {
      tJ -= (tI + 1);
      tI++;
    }
    const int i0 = tI * 64, jj0 = tJ * 64;
    const int txl = tid & 15, tyl = tid >> 4;

    double(*Ea)[33] = (double(*)[33])sh;           // 64x33
    double(*Eb)[33] = (double(*)[33])(sh + 2112);  // 64x33

    for (int e = tid; e < 64 * 32; e += 256) {
      int r = e >> 5, c = e & 31;
      Ea[r][c] = (i0 + r < S) ? A[(size_t)(o + i0 + r) * DD + pj + c] : 0.0;
      Eb[r][c] = (jj0 + r < S) ? A[(size_t)(o + jj0 + r) * DD + pj + c] : 0.0;
    }
    __syncthreads();

    double s[4][4];
#pragma unroll
    for (int i = 0; i < 4; ++i)
#pragma unroll
      for (int j = 0; j < 4; ++j) s[i][j] = 0.0;

    const int bi = tyl * 4, bj = txl * 4;
#pragma unroll
    for (int k = 0; k < 32; ++k) {
      double a[4], bv[4];
#pragma unroll
      for (int i = 0; i < 4; ++i) a[i] = Ea[bi + i][k];
#pragma unroll
      for (int j = 0; j < 4; ++j) bv[j] = Eb[bj + j][k];
#pragma unroll
      for (int i = 0; i < 4; ++i)
#pragma unroll
        for (int j = 0; j < 4; ++j) s[i][j] = fma(a[i], bv[j], s[i][j]);
    }

#pragma unroll
    for (int i = 0; i < 4; ++i)
#pragma unroll
      for (int j = 0; j < 4; ++j) {
        int gi = i0 + bi + i, gj = jj0 + bj + j;
        if (gi < S && gj < S && gi >= gj)
          A[(size_t)(o + gi) * DD + (o + gj)] -= s[i][j];
      }
  }
}

extern "C" void kernel_launch(void* const* d_in, const int* in_sizes, int n_in,
                              void* d_out, int out_size, void* d_ws,
                              size_t ws_size, hipStream_t stream) {
  const float* x = (const float*)d_in[0];
  const float* w = (const float*)d_in[1];
  const float* gamma = (const float*)d_in[2];
  const float* beta = (const float*)d_in[3];
  const float* rmean = (const float*)d_in[4];
  const float* rvar = (const float*)d_in[5];
  float* out = (float*)d_out;

  char* ws = (char*)d_ws;
  float* yt = (float*)ws;                           // 12,845,056 B
  double* cov = (double*)(ws + 12845056 + 131072);  // 33,554,432 B
  // alias W-prep buffers into cov (consumed by k_conv before cov is written)
  unsigned short* wh = (unsigned short*)cov;  // 1,048,576 B
  unsigned short* wl = wh + (DD * CC);        // 1,048,576 B
  float* sclv = (float*)(wl + (DD * CC));     //     1,024 B
  float* sftv = sclv + DD;                    //     1,024 B

  k_prep<<<512, 256, 0, stream>>>(w, gamma, beta, rmean, rvar, wh, wl, sclv,
                                  sftv);
  k_conv<<<NTOT / 64, 256, 0, stream>>>(x, wh, wl, sclv, sftv, yt);
  k_cov<<<dim3(BB, 10), 256, 0, stream>>>(yt, cov);
  for (int kb = 0; kb < 8; ++kb) {
    int ntiles = 0;
    if (kb > 0) {
      int S = DD - (kb * 32 + 32);
      if (S > 0) {
        int nt = (S + 63) / 64;
        ntiles = nt * (nt + 1) / 2;
      }
    }
    k_panel3<<<dim3(BB, 1 + ntiles), 256, 0, stream>>>(cov, out, kb);
  }
}

// Round 7
// 604.532 us; speedup vs baseline: 1.6524x; 1.0793x over previous
//
#include <hip/hip_runtime.h>
#include <math.h>

#define BB 64
#define CC 2048
#define MM 196
#define DD 256
#define NTOT (BB * MM)  // 12544

typedef __attribute__((ext_vector_type(8))) short short8;
typedef __attribute__((ext_vector_type(4))) short short4v;
typedef __attribute__((ext_vector_type(4))) unsigned short ushort4v;
typedef __attribute__((ext_vector_type(4))) float f32x4;

__device__ __forceinline__ unsigned short bf16_rne(float f) {
  unsigned int u = __float_as_uint(f);
  unsigned int r = u + 0x7FFFu + ((u >> 16) & 1u);
  return (unsigned short)(r >> 16);
}

// ---------------------------------------------------------------------------
// K0: prep — split W into bf16 hi/lo (wh+wl), precompute BN scale/shift.
// (R0-proven verbatim)
// ---------------------------------------------------------------------------
__global__ __launch_bounds__(256) void k_prep(
    const float* __restrict__ w, const float* __restrict__ gamma,
    const float* __restrict__ beta, const float* __restrict__ rmean,
    const float* __restrict__ rvar, unsigned short* __restrict__ wh,
    unsigned short* __restrict__ wl, float* __restrict__ sclv,
    float* __restrict__ sftv) {
  const int e0 = (blockIdx.x * 256 + threadIdx.x) * 4;
  f32x4 v = *(const f32x4*)(w + e0);
  ushort4v h, l;
#pragma unroll
  for (int i = 0; i < 4; ++i) {
    unsigned short hb = bf16_rne(v[i]);
    float hf = __uint_as_float((unsigned int)hb << 16);
    h[i] = hb;
    l[i] = bf16_rne(v[i] - hf);
  }
  *(ushort4v*)(wh + e0) = h;
  *(ushort4v*)(wl + e0) = l;
  if (blockIdx.x == 0 && threadIdx.x < DD) {
    int d = threadIdx.x;
    float s = gamma[d] / sqrtf(rvar[d] + 1e-5f);
    sclv[d] = s;
    sftv[d] = beta[d] - rmean[d] * s;
  }
}

// ---------------------------------------------------------------------------
// K1: conv+BN+ReLU via bf16 split-3 MFMA (R6 double-buffered version,
// 136.5 us measured).
// ---------------------------------------------------------------------------
__global__ __launch_bounds__(256, 2) void k_conv(
    const float* __restrict__ x, const unsigned short* __restrict__ wh,
    const unsigned short* __restrict__ wl, const float* __restrict__ sclv,
    const float* __restrict__ sftv, float* __restrict__ yt) {
  const int tid = threadIdx.x;
  const int wid = tid >> 6, lane = tid & 63;
  const int quad = lane >> 4, l16 = lane & 15;
  const int n0 = blockIdx.x * 64;

  __shared__ unsigned short Xh[2][64][36];
  __shared__ unsigned short Xl[2][64][36];

  f32x4 acc[4][4];
#pragma unroll
  for (int i = 0; i < 4; ++i)
#pragma unroll
    for (int j = 0; j < 4; ++j) acc[i][j] = (f32x4)0.f;

  const int nX = tid & 63, kq = tid >> 6;
  const int gn = n0 + nX;
  const int bX = gn / MM, mX = gn - bX * MM;
  const float* xp = x + (size_t)bX * CC * MM + mX;

  size_t aoff[4];
#pragma unroll
  for (int ds = 0; ds < 4; ++ds)
    aoff[ds] = (size_t)(wid * 64 + ds * 16 + l16) * CC + quad * 8;

  short8 Ah[4], Al[4], Ah2[4], Al2[4];
#pragma unroll
  for (int ds = 0; ds < 4; ++ds) {
    Ah[ds] = *(const short8*)(wh + aoff[ds]);
    Al[ds] = *(const short8*)(wl + aoff[ds]);
  }

  float xr[8];
#pragma unroll
  for (int p = 0; p < 8; ++p) xr[p] = xp[(size_t)(kq * 8 + p) * MM];
  {
    ushort4v h0, h1, l0, l1;
#pragma unroll
    for (int p = 0; p < 4; ++p) {
      unsigned short hb = bf16_rne(xr[p]);
      float hf = __uint_as_float((unsigned int)hb << 16);
      h0[p] = hb;
      l0[p] = bf16_rne(xr[p] - hf);
    }
#pragma unroll
    for (int p = 0; p < 4; ++p) {
      unsigned short hb = bf16_rne(xr[4 + p]);
      float hf = __uint_as_float((unsigned int)hb << 16);
      h1[p] = hb;
      l1[p] = bf16_rne(xr[4 + p] - hf);
    }
    *(ushort4v*)&Xh[0][nX][kq * 8] = h0;
    *(ushort4v*)&Xh[0][nX][kq * 8 + 4] = h1;
    *(ushort4v*)&Xl[0][nX][kq * 8] = l0;
    *(ushort4v*)&Xl[0][nX][kq * 8 + 4] = l1;
  }
#pragma unroll
  for (int p = 0; p < 8; ++p) xr[p] = xp[(size_t)(32 + kq * 8 + p) * MM];
  __syncthreads();

  for (int c = 0; c < 64; ++c) {
    const int buf = c & 1;
    if (c < 63) {
      ushort4v h0, h1, l0, l1;
#pragma unroll
      for (int p = 0; p < 4; ++p) {
        unsigned short hb = bf16_rne(xr[p]);
        float hf = __uint_as_float((unsigned int)hb << 16);
        h0[p] = hb;
        l0[p] = bf16_rne(xr[p] - hf);
      }
#pragma unroll
      for (int p = 0; p < 4; ++p) {
        unsigned short hb = bf16_rne(xr[4 + p]);
        float hf = __uint_as_float((unsigned int)hb << 16);
        h1[p] = hb;
        l1[p] = bf16_rne(xr[4 + p] - hf);
      }
      *(ushort4v*)&Xh[buf ^ 1][nX][kq * 8] = h0;
      *(ushort4v*)&Xh[buf ^ 1][nX][kq * 8 + 4] = h1;
      *(ushort4v*)&Xl[buf ^ 1][nX][kq * 8] = l0;
      *(ushort4v*)&Xl[buf ^ 1][nX][kq * 8 + 4] = l1;
      if (c < 62) {
#pragma unroll
        for (int p = 0; p < 8; ++p)
          xr[p] = xp[(size_t)((c + 2) * 32 + kq * 8 + p) * MM];
      }
#pragma unroll
      for (int ds = 0; ds < 4; ++ds) {
        Ah2[ds] = *(const short8*)(wh + aoff[ds] + (c + 1) * 32);
        Al2[ds] = *(const short8*)(wl + aoff[ds] + (c + 1) * 32);
      }
    }
#pragma unroll
    for (int ns = 0; ns < 4; ++ns) {
      const unsigned short* bp = &Xh[buf][ns * 16 + l16][quad * 8];
      short4v b0 = *(const short4v*)bp;
      short4v b1 = *(const short4v*)(bp + 4);
      short8 Bh = __builtin_shufflevector(b0, b1, 0, 1, 2, 3, 4, 5, 6, 7);
      const unsigned short* bq = &Xl[buf][ns * 16 + l16][quad * 8];
      short4v c0 = *(const short4v*)bq;
      short4v c1 = *(const short4v*)(bq + 4);
      short8 Bl = __builtin_shufflevector(c0, c1, 0, 1, 2, 3, 4, 5, 6, 7);
#pragma unroll
      for (int ds = 0; ds < 4; ++ds) {
        acc[ds][ns] = __builtin_amdgcn_mfma_f32_16x16x32_bf16(
            Ah[ds], Bh, acc[ds][ns], 0, 0, 0);
        acc[ds][ns] = __builtin_amdgcn_mfma_f32_16x16x32_bf16(
            Ah[ds], Bl, acc[ds][ns], 0, 0, 0);
        acc[ds][ns] = __builtin_amdgcn_mfma_f32_16x16x32_bf16(
            Al[ds], Bh, acc[ds][ns], 0, 0, 0);
      }
    }
    __syncthreads();
    if (c < 63) {
#pragma unroll
      for (int ds = 0; ds < 4; ++ds) {
        Ah[ds] = Ah2[ds];
        Al[ds] = Al2[ds];
      }
    }
  }

#pragma unroll
  for (int ds = 0; ds < 4; ++ds) {
    const int dbase = wid * 64 + ds * 16 + quad * 4;
    f32x4 s4 = *(const f32x4*)(sclv + dbase);
    f32x4 f4 = *(const f32x4*)(sftv + dbase);
#pragma unroll
    for (int ns = 0; ns < 4; ++ns) {
      const int n = n0 + ns * 16 + l16;
      const int b = n / MM, m = n - b * MM;
      f32x4 o;
#pragma unroll
      for (int r = 0; r < 4; ++r) {
        float v = fmaf(acc[ds][ns][r], s4[r], f4[r]);
        o[r] = v > 0.f ? v : 0.f;
      }
      *(f32x4*)(yt + ((size_t)b * MM + m) * DD + dbase) = o;
    }
  }
}

// ---------------------------------------------------------------------------
// K3: cov[b] = (Y-mu)(Y-mu)^T / M + eps*I in fp64, with fused in-kernel mean
// (R6-proven).
// ---------------------------------------------------------------------------
__global__ __launch_bounds__(256) void k_cov(const float* __restrict__ yt,
                                             double* __restrict__ cov) {
  const int b = blockIdx.x;
  const int t = blockIdx.y;
  const int ti = (t < 1) ? 0 : (t < 3) ? 1 : (t < 6) ? 2 : 3;
  const int tj = t - (ti * (ti + 1)) / 2;
  const int i0 = ti * 64, j0 = tj * 64;
  const int tid = threadIdx.x;
  const int tx = tid & 15, ty = tid >> 4;

  __shared__ double As[32][66];
  __shared__ double Bs[32][66];
  __shared__ double Ms[4][64];

  double acc[4][4];
#pragma unroll
  for (int i = 0; i < 4; ++i)
#pragma unroll
    for (int j = 0; j < 4; ++j) acc[i][j] = 0.0;

  const int dl = tid & 63, kl = tid >> 6;
  const float* ybase = yt + (size_t)b * MM * DD;

  {
    const int base_d = ((kl < 2) ? i0 : j0) + dl;
    const int mlo = (kl & 1) ? 98 : 0;
    const int mhi = (kl & 1) ? 196 : 98;
    double s = 0.0;
    for (int m = mlo; m < mhi; ++m)
      s += (double)ybase[(size_t)m * DD + base_d];
    Ms[kl][dl] = s;
  }
  __syncthreads();
  const double mA = (Ms[0][dl] + Ms[1][dl]) * (1.0 / MM);
  const double mB = (Ms[2][dl] + Ms[3][dl]) * (1.0 / MM);

  for (int k0 = 0; k0 < MM; k0 += 32) {
    __syncthreads();
#pragma unroll
    for (int p = 0; p < 8; ++p) {
      int k = kl + p * 4;
      int m = k0 + k;
      double av = 0.0, bv = 0.0;
      if (m < MM) {
        av = (double)ybase[(size_t)m * DD + i0 + dl] - mA;
        bv = (double)ybase[(size_t)m * DD + j0 + dl] - mB;
      }
      As[k][dl] = av;
      Bs[k][dl] = bv;
    }
    __syncthreads();
#pragma unroll
    for (int k = 0; k < 32; ++k) {
      double a[4], bv[4];
#pragma unroll
      for (int i = 0; i < 4; ++i) a[i] = As[k][ty * 4 + i];
#pragma unroll
      for (int j = 0; j < 4; ++j) bv[j] = Bs[k][tx * 4 + j];
#pragma unroll
      for (int i = 0; i < 4; ++i)
#pragma unroll
        for (int j = 0; j < 4; ++j) acc[i][j] = fma(a[i], bv[j], acc[i][j]);
    }
  }

  double* cb = cov + (size_t)b * DD * DD;
#pragma unroll
  for (int i = 0; i < 4; ++i) {
#pragma unroll
    for (int j = 0; j < 4; ++j) {
      int gi = i0 + ty * 4 + i, gj = j0 + tx * 4 + j;
      double v = acc[i][j] * (1.0 / MM);
      if (gi == gj) v += 1e-6;
      cb[(size_t)gi * DD + gj] = v;
      if (ti != tj) cb[(size_t)gj * DD + gi] = v;
    }
  }
}

// ---------------------------------------------------------------------------
// K4: lookahead Cholesky step kb (register panel, 33.8KB LDS).  Out-phase
// REMOVED (R6 post-mortem: fusing it into the 64-block kb=7 dispatch cost
// ~130 us at 0.02% occupancy — tile parallelism >> launch count).
// ---------------------------------------------------------------------------
__global__ __launch_bounds__(256) void k_panel3(double* __restrict__ cov,
                                                int kb) {
  const int b = blockIdx.x;
  double* A = cov + (size_t)b * DD * DD;
  const int j0 = kb * 32;
  const int tid = threadIdx.x;

  __shared__ double sh[4224];  // 33,792 B union

  if (blockIdx.y == 0) {
    double(*LpTop)[33] = (double(*)[33])sh;          // 32x33
    double(*L11s)[33] = (double(*)[33])(sh + 1056);  // 32x33
    double* rpivs = sh + 2112;
    const int R = DD - j0;
    const int pj = j0 - 32;

    double sp[32];
    const double* rowp = A + (size_t)(j0 + tid) * DD;
    if (tid < R) {
#pragma unroll
      for (int c = 0; c < 32; ++c) sp[c] = rowp[j0 + c];
    }

    if (kb > 0) {
      double lp[32];
      if (tid < R) {
#pragma unroll
        for (int c = 0; c < 32; ++c) lp[c] = rowp[pj + c];
      }
      if (tid < 32) {
#pragma unroll
        for (int c = 0; c < 32; ++c) LpTop[tid][c] = lp[c];
      }
      __syncthreads();
      if (tid < R) {
#pragma unroll
        for (int c = 0; c < 32; ++c) {
          double a = 0.0;
#pragma unroll
          for (int p = 0; p < 32; ++p) a = fma(lp[p], LpTop[c][p], a);
          sp[c] -= a;
        }
      }
    }

    if (tid < 32) {
      double rpkeep = 0.0;
#pragma unroll
      for (int j = 0; j < 32; ++j) {
        double dj = __shfl(sp[j], j);
        double piv = sqrt(dj);
        double rp = 1.0 / piv;
        if (tid == j) {
          sp[j] = piv;
          rpkeep = rp;
        } else {
          sp[j] = sp[j] * rp;
        }
        double lij = sp[j];
#pragma unroll
        for (int k = j + 1; k < 32; ++k) {
          double ck = __shfl(lij, k);
          sp[k] -= lij * ck;
        }
      }
#pragma unroll
      for (int k = 0; k < 32; ++k) L11s[tid][k] = (k <= tid) ? sp[k] : 0.0;
      rpivs[tid] = rpkeep;
      for (int k = 0; k <= tid; ++k)
        A[(size_t)(j0 + tid) * DD + j0 + k] = sp[k];
    }
    __syncthreads();

    if (tid >= 32 && tid < R) {
#pragma unroll
      for (int j = 0; j < 32; ++j) {
        double s = sp[j];
#pragma unroll
        for (int k = 0; k < 32; ++k)
          if (k < j) s -= sp[k] * L11s[j][k];
        sp[j] = s * rpivs[j];
      }
      double* dst = A + (size_t)(j0 + tid) * DD + j0;
#pragma unroll
      for (int k = 0; k < 32; ++k) dst[k] = sp[k];
    }
  } else {
    // trailing: apply panel kb-1 to [o,256)^2 (R0-proven verbatim, Ea/Eb)
    const int o = j0 + 32;
    const int S = DD - o;
    const int pj = j0 - 32;
    int tI = 0, tJ = (int)blockIdx.y - 1;
    while (tJ > tI) {
      tJ -= (tI + 1);
      tI++;
    }
    const int i0 = tI * 64, jj0 = tJ * 64;
    const int txl = tid & 15, tyl = tid >> 4;

    double(*Ea)[33] = (double(*)[33])sh;           // 64x33
    double(*Eb)[33] = (double(*)[33])(sh + 2112);  // 64x33

    for (int e = tid; e < 64 * 32; e += 256) {
      int r = e >> 5, c = e & 31;
      Ea[r][c] = (i0 + r < S) ? A[(size_t)(o + i0 + r) * DD + pj + c] : 0.0;
      Eb[r][c] = (jj0 + r < S) ? A[(size_t)(o + jj0 + r) * DD + pj + c] : 0.0;
    }
    __syncthreads();

    double s[4][4];
#pragma unroll
    for (int i = 0; i < 4; ++i)
#pragma unroll
      for (int j = 0; j < 4; ++j) s[i][j] = 0.0;

    const int bi = tyl * 4, bj = txl * 4;
#pragma unroll
    for (int k = 0; k < 32; ++k) {
      double a[4], bv[4];
#pragma unroll
      for (int i = 0; i < 4; ++i) a[i] = Ea[bi + i][k];
#pragma unroll
      for (int j = 0; j < 4; ++j) bv[j] = Eb[bj + j][k];
#pragma unroll
      for (int i = 0; i < 4; ++i)
#pragma unroll
        for (int j = 0; j < 4; ++j) s[i][j] = fma(a[i], bv[j], s[i][j]);
    }

#pragma unroll
    for (int i = 0; i < 4; ++i)
#pragma unroll
      for (int j = 0; j < 4; ++j) {
        int gi = i0 + bi + i, gj = jj0 + bj + j;
        if (gi < S && gj < S && gi >= gj)
          A[(size_t)(o + gi) * DD + (o + gj)] -= s[i][j];
      }
  }
}

// ---------------------------------------------------------------------------
// K5: out[b, triu(i,j)] = (i==j) ? 2*log(L[ii]) : L[j][i], fp32, coalesced.
// (R0-proven verbatim: grid (10, BB) = 640 blocks.)
// ---------------------------------------------------------------------------
__global__ __launch_bounds__(256) void k_out(const double* __restrict__ cov,
                                             float* __restrict__ out) {
  const int b = blockIdx.y;
  int t = blockIdx.x;
  int ti = 0, tj = t;
  while (tj >= 4 - ti) {
    tj -= (4 - ti);
    ti++;
  }
  tj += ti;
  const int tid = threadIdx.x;
  const double* A = cov + (size_t)b * DD * DD;

  __shared__ float S[64][65];
  for (int e = tid; e < 4096; e += 256) {
    int jj = e >> 6, ii = e & 63;
    S[jj][ii] = (float)A[(size_t)(tj * 64 + jj) * DD + ti * 64 + ii];
  }
  __syncthreads();

  for (int e = tid; e < 4096; e += 256) {
    int ii = e >> 6, jj = e & 63;
    int i = ti * 64 + ii, j = tj * 64 + jj;
    if (j < i) continue;
    float v = S[jj][ii];
    if (i == j) v = 2.0f * logf(v);
    int off = i * DD - (i * (i - 1)) / 2 + (j - i);
    out[(size_t)b * 32896 + off] = v;
  }
}

extern "C" void kernel_launch(void* const* d_in, const int* in_sizes, int n_in,
                              void* d_out, int out_size, void* d_ws,
                              size_t ws_size, hipStream_t stream) {
  const float* x = (const float*)d_in[0];
  const float* w = (const float*)d_in[1];
  const float* gamma = (const float*)d_in[2];
  const float* beta = (const float*)d_in[3];
  const float* rmean = (const float*)d_in[4];
  const float* rvar = (const float*)d_in[5];
  float* out = (float*)d_out;

  char* ws = (char*)d_ws;
  float* yt = (float*)ws;                           // 12,845,056 B
  double* cov = (double*)(ws + 12845056 + 131072);  // 33,554,432 B
  // alias W-prep buffers into cov (consumed by k_conv before cov is written)
  unsigned short* wh = (unsigned short*)cov;  // 1,048,576 B
  unsigned short* wl = wh + (DD * CC);        // 1,048,576 B
  float* sclv = (float*)(wl + (DD * CC));     //     1,024 B
  float* sftv = sclv + DD;                    //     1,024 B

  k_prep<<<512, 256, 0, stream>>>(w, gamma, beta, rmean, rvar, wh, wl, sclv,
                                  sftv);
  k_conv<<<NTOT / 64, 256, 0, stream>>>(x, wh, wl, sclv, sftv, yt);
  k_cov<<<dim3(BB, 10), 256, 0, stream>>>(yt, cov);
  for (int kb = 0; kb < 8; ++kb) {
    int ntiles = 0;
    if (kb > 0) {
      int S = DD - (kb * 32 + 32);
      if (S > 0) {
        int nt = (S + 63) / 64;
        ntiles = nt * (nt + 1) / 2;
      }
    }
    k_panel3<<<dim3(BB, 1 + ntiles), 256, 0, stream>>>(cov, kb);
  }
  k_out<<<dim3(10, BB), 256, 0, stream>>>(cov, out);
}